// Round 14
// baseline (1140.391 us; speedup 1.0000x reference)
//
#include <hip/hip_runtime.h>
#include <math.h>

#define NL 4
#define DM 1024
#define NH 8
#define HD 128
#define BB 8
#define LL 512
#define MM (BB*LL)      // 4096 rows
#define PEN (2*LL)      // 1024 pe rows
#define QT 32           // q rows per attn block (2 waves x 16)
#define KT 32           // k tile
#define NKT (LL/KT)     // 16
#define VS 44           // Vt LDS row stride (shorts)

typedef __attribute__((ext_vector_type(8))) __bf16 bf16x8;
typedef __attribute__((ext_vector_type(4))) float f32x4;

// ---------------- helpers ----------------
__device__ __forceinline__ unsigned short f2b(float f) {   // RNE f32->bf16
  unsigned int u = __float_as_uint(f);
  u = (u + 0x7FFFu + ((u >> 16) & 1u)) >> 16;
  return (unsigned short)u;
}
__device__ __forceinline__ float b2f(unsigned short s) {
  return __uint_as_float(((unsigned int)s) << 16);
}
__device__ __forceinline__ void glds16(const void* g, void* l) {
  __builtin_amdgcn_global_load_lds(
      (const __attribute__((address_space(1))) unsigned int*)g,
      (__attribute__((address_space(3))) unsigned int*)l, 16, 0, 0);
}
union U8 { unsigned short s[8]; bf16x8 v; };
// trunc-hi / RNE-lo split of 8 floats
__device__ __forceinline__ void split8(const float4& a, const float4& b,
                                       bf16x8& h, bf16x8& l) {
  float x[8] = {a.x,a.y,a.z,a.w,b.x,b.y,b.z,b.w};
  U8 uh, ul;
#pragma unroll
  for (int e = 0; e < 8; ++e) {
    unsigned u = __float_as_uint(x[e]);
    uh.s[e] = (unsigned short)(u >> 16);
    ul.s[e] = f2b(x[e] - __uint_as_float(u & 0xffff0000u));
  }
  h = uh.v; l = ul.v;
}

// -------- relative position embedding (RNE hi + RNE residual lo) ----------
__global__ __launch_bounds__(256) void pe_kernel(unsigned short* __restrict__ peh,
                                                 unsigned short* __restrict__ pel) {
  int idx = blockIdx.x * 256 + threadIdx.x;
  if (idx >= PEN * HD) return;
  int p = idx / HD, j = idx % HD;
  int tt = (j < 64) ? j : (j - 64);
  float invf = expf((float)tt * (-9.210340371976184f / 63.0f));
  float ang = (float)(p - LL) * invf;
  float v = (j < 64) ? sinf(ang) : cosf(ang);
  unsigned short h = f2b(v);
  peh[idx] = h;
  pel[idx] = f2b(v - b2f(h));
}

// ---------------- d2[n][p] = (rw[n]-rr[n]) . pe[p] ----------------
__global__ __launch_bounds__(256) void d2_kernel(const float* __restrict__ rrb,
                                                 const float* __restrict__ rwb,
                                                 const unsigned short* __restrict__ peh,
                                                 const unsigned short* __restrict__ pel,
                                                 float* __restrict__ d2) {
  int idx = blockIdx.x * 256 + threadIdx.x;
  if (idx >= NH * PEN) return;
  int n = idx / PEN, p = idx % PEN;
  float s = 0.f;
  for (int d = 0; d < HD; ++d) {
    float pv = b2f(peh[p*HD + d]) + b2f(pel[p*HD + d]);
    s += (rwb[n*HD + d] - rrb[n*HD + d]) * pv;
  }
  d2[idx] = s;
}

// ---------------- split f32 -> (hi,lo) bf16 pair, RNE ----------------
__global__ __launch_bounds__(256) void split_kernel(const float* __restrict__ in,
                                                    unsigned short* __restrict__ hi,
                                                    unsigned short* __restrict__ lo,
                                                    int n) {
  int i = (blockIdx.x * 256 + threadIdx.x) * 4;
  if (i >= n) return;
  float4 v = *(const float4*)&in[i];
  float x[4] = {v.x, v.y, v.z, v.w};
  ushort4 h4, l4;
  unsigned short* hp = (unsigned short*)&h4;
  unsigned short* lp = (unsigned short*)&l4;
#pragma unroll
  for (int e = 0; e < 4; ++e) {
    unsigned short h = f2b(x[e]);
    hp[e] = h;
    lp[e] = f2b(x[e] - b2f(h));
  }
  *(ushort4*)&hi[i] = h4;
  *(ushort4*)&lo[i] = l4;
}

// ---------------- split-bf16 MFMA GEMM: C = A[M][K] @ Bw[N][K]^T -----------
// BK=64, A via global_load_lds (linear dest + source-seg swizzle), B
// reg-staged pad 72. XCD-chunked block swizzle. FFN=false: columns <DM go
// f32 to C (ldc=DM); columns >=DM are split into Vhi/Vlo. FFN=true: f32 +
// bias + relu to C.
template<bool FFN>
__global__ __launch_bounds__(256) void gemm_mfma(
    const unsigned short* __restrict__ Ah, const unsigned short* __restrict__ Al,
    const float* __restrict__ Bw, const float* __restrict__ bias,
    float* __restrict__ C, unsigned short* __restrict__ Vhi,
    unsigned short* __restrict__ Vlo, int N, int K, int ldc) {
  __shared__ __align__(16) unsigned short AsH[128*64];
  __shared__ __align__(16) unsigned short AsL[128*64];
  __shared__ __align__(16) unsigned short BsH[128*72];
  __shared__ __align__(16) unsigned short BsL[128*72];
  const int t = threadIdx.x;
  const int w = t >> 6, l = t & 63;
  const int gx = gridDim.x;
  const int nwg = gx * gridDim.y;
  const int id = blockIdx.y * gx + blockIdx.x;
  const int swz = (id & 7) * (nwg >> 3) + (id >> 3);
  const int bm = (swz / gx) * 128, bn = (swz % gx) * 128;
  const int wr = (w >> 1) * 64, wc = (w & 1) * 64;

  const int aseg = ((t & 7) ^ ((t >> 3) & 7)) * 8;
  const unsigned short* Ahb = Ah + (size_t)(bm + (t >> 3)) * K + aseg;
  const unsigned short* Alb = Al + (size_t)(bm + (t >> 3)) * K + aseg;

  const int brow = t >> 1, bhalf = (t & 1) * 32;
  const float* Bb = Bw + (size_t)(bn + brow) * K + bhalf;

  f32x4 acc[4][4] = {};
  const int lm = l & 15;
  const int lg = l >> 4;

  for (int k0 = 0; k0 < K; k0 += 64) {
    float4 bv[8];
#pragma unroll
    for (int c = 0; c < 8; ++c)
      bv[c] = *(const float4*)(Bb + k0 + c*4);
#pragma unroll
    for (int i = 0; i < 4; ++i) {
      glds16(Ahb + (size_t)(i*32)*K + k0, &AsH[w*512 + i*2048]);
      glds16(Alb + (size_t)(i*32)*K + k0, &AsL[w*512 + i*2048]);
    }
#pragma unroll
    for (int c = 0; c < 8; ++c) {
      float xs[4] = {bv[c].x, bv[c].y, bv[c].z, bv[c].w};
      ushort4 h4, l4;
      unsigned short* hp = (unsigned short*)&h4;
      unsigned short* lp = (unsigned short*)&l4;
#pragma unroll
      for (int e = 0; e < 4; ++e) {
        unsigned u = __float_as_uint(xs[e]);
        hp[e] = (unsigned short)(u >> 16);
        float r = xs[e] - __uint_as_float(u & 0xffff0000u);
        lp[e] = (unsigned short)(__float_as_uint(r) >> 16);
      }
      *(ushort4*)&BsH[brow*72 + bhalf + c*4] = h4;
      *(ushort4*)&BsL[brow*72 + bhalf + c*4] = l4;
    }
    __syncthreads();

#pragma unroll
    for (int kk = 0; kk < 2; ++kk) {
      bf16x8 afh[4], afl[4], bfh[4], bfl[4];
#pragma unroll
      for (int i = 0; i < 4; ++i) {
        const int row = wr + i*16 + lm;
        const int sw = ((kk*4 + lg) ^ (lm & 7)) * 8;
        afh[i] = *(const bf16x8*)&AsH[row*64 + sw];
        afl[i] = *(const bf16x8*)&AsL[row*64 + sw];
      }
#pragma unroll
      for (int j = 0; j < 4; ++j) {
        bfh[j] = *(const bf16x8*)&BsH[(wc + j*16 + lm)*72 + kk*32 + lg*8];
        bfl[j] = *(const bf16x8*)&BsL[(wc + j*16 + lm)*72 + kk*32 + lg*8];
      }
#pragma unroll
      for (int i = 0; i < 4; ++i)
#pragma unroll
        for (int j = 0; j < 4; ++j) {
          acc[i][j] = __builtin_amdgcn_mfma_f32_16x16x32_bf16(afh[i], bfh[j], acc[i][j], 0, 0, 0);
          acc[i][j] = __builtin_amdgcn_mfma_f32_16x16x32_bf16(afh[i], bfl[j], acc[i][j], 0, 0, 0);
          acc[i][j] = __builtin_amdgcn_mfma_f32_16x16x32_bf16(afl[i], bfh[j], acc[i][j], 0, 0, 0);
        }
    }
    __syncthreads();
  }

  const int cr = (l >> 4) * 4;
  const bool vhalf = (!FFN) && (bn >= DM);   // block-uniform
#pragma unroll
  for (int i = 0; i < 4; ++i) {
#pragma unroll
    for (int j = 0; j < 4; ++j) {
      int row = bm + wr + i*16 + cr;
      int col = bn + wc + j*16 + lm;
      float bvl = FFN ? bias[col] : 0.f;
      f32x4 a = acc[i][j];
#pragma unroll
      for (int r4 = 0; r4 < 4; ++r4) {
        float v = a[r4];
        if (FFN) {
          v = fmaxf(v + bvl, 0.f);
          C[(size_t)(row + r4) * ldc + col] = v;
        } else if (vhalf) {
          unsigned u = __float_as_uint(v);
          size_t off = (size_t)(row + r4) * DM + (col - DM);
          Vhi[off] = (unsigned short)(u >> 16);
          Vlo[off] = f2b(v - __uint_as_float(u & 0xffff0000u));
        } else {
          C[(size_t)(row + r4) * ldc + col] = v;
        }
      }
    }
  }
}

// ================= MFMA fused relative attention (v11) =================
// QT=32, 128 threads (2 waves), grid (NH, LL/32, BB) = 1024 blocks ->
// 4 blocks/CU exactly resident (same 8 waves/CU as before but 4
// independent k-loop chains and 2-wave barrier scope). K-hi stays in LDS;
// K-lo B-frags are read per-tile straight from global/L2 (same per-lane
// 16B gather pattern as the pe loads), consumed in a reordered 3rd AC
// pass after ~16 covering MFMAs. LDS 36.3 KB. XCD grouping: n=blockIdx.x
// -> linear id % 8 == n (all 16 qt-blocks of one (n,b) on one XCD).
__global__ __launch_bounds__(128, 2) void attn_mfma(
    const float* __restrict__ qbuf,         // [MM][1024] f32 q (also output)
    const unsigned short* __restrict__ khp, // keys hi  [MM][1024]
    const unsigned short* __restrict__ klp, // keys lo
    const unsigned short* __restrict__ vhp, // v hi [MM][1024]
    const unsigned short* __restrict__ vlp, // v lo
    const unsigned short* __restrict__ pehp,// [1024][128] bf16 hi
    const unsigned short* __restrict__ pelp,// [1024][128] bf16 lo
    const float* __restrict__ rrb,          // [NH][128] layer slice
    const int*   __restrict__ mask,         // [BB][LL]
    const float* __restrict__ d2p,          // [NH][1024]
    float* __restrict__ outp)               // = qbuf (stride 1024)
{
  __shared__ __align__(16) unsigned short KsH[KT*136];   // 8.7 KB (hi only)
  __shared__ __align__(16) unsigned short VtH[HD*VS];    // 11.3 KB
  __shared__ __align__(16) unsigned short VtL[HD*VS];    // 11.3 KB
  __shared__ __align__(16) unsigned short PsH[2][16*40]; // 2.6 KB
  __shared__ __align__(16) unsigned short PsL[2][16*40]; // 2.6 KB
  // total ~36.3 KB -> 4 blocks/CU

  const int n  = blockIdx.x;        // XCD key: linear id % 8 == n
  const int qt = blockIdx.y;
  const int b  = blockIdx.z;
  const int q0 = qt * QT;
  const int t  = threadIdx.x;       // 0..127
  const int w  = t >> 6, l = t & 63;
  const int lm = l & 15, lg = l >> 4;
  const int q0w = q0 + w*16;
  const int kr  = t >> 2, ks = (t & 3) * 32;      // K staging: row, seg base
  const int vr0 = (t >> 5) * 8, vd4 = (t & 31)*4; // V staging: rows, dim

  // ---- qa A-frags in registers (split hi/lo) ----
  bf16x8 qah[4], qal[4];
  {
    size_t qrow = (size_t)(b*LL + q0w + lm) * DM + (size_t)n*HD;
#pragma unroll
    for (int c = 0; c < 4; ++c) {
      int d0 = c*32 + lg*8;
      float4 x1 = *(const float4*)&qbuf[qrow + d0];
      float4 x2 = *(const float4*)&qbuf[qrow + d0 + 4];
      float4 r1 = *(const float4*)&rrb[n*HD + d0];
      float4 r2 = *(const float4*)&rrb[n*HD + d0 + 4];
      float4 a = {x1.x+r1.x, x1.y+r1.y, x1.z+r1.z, x1.w+r1.w};
      float4 bq = {x2.x+r2.x, x2.y+r2.y, x2.z+r2.z, x2.w+r2.w};
      split8(a, bq, qah[c], qal[c]);
    }
  }

  // ---- prologue staging: K-hi / V tile 0 ----
  {
    size_t krow = (size_t)(b*LL + kr)*DM + (size_t)n*HD + ks;
#pragma unroll
    for (int i = 0; i < 4; ++i)
      *(uint4*)&KsH[kr*136 + ks + i*8] = *(const uint4*)&khp[krow + i*8];
    ushort4 vh[8], vl[8];
#pragma unroll
    for (int i = 0; i < 8; ++i) {
      size_t vrow = (size_t)(b*LL + vr0 + i)*DM + n*HD + vd4;
      vh[i] = *(const ushort4*)&vhp[vrow];
      vl[i] = *(const ushort4*)&vlp[vrow];
    }
#pragma unroll
    for (int e = 0; e < 4; ++e) {
      ushort4 ta = { ((const unsigned short*)&vh[0])[e], ((const unsigned short*)&vh[1])[e],
                     ((const unsigned short*)&vh[2])[e], ((const unsigned short*)&vh[3])[e] };
      ushort4 tb = { ((const unsigned short*)&vh[4])[e], ((const unsigned short*)&vh[5])[e],
                     ((const unsigned short*)&vh[6])[e], ((const unsigned short*)&vh[7])[e] };
      ushort4 tc = { ((const unsigned short*)&vl[0])[e], ((const unsigned short*)&vl[1])[e],
                     ((const unsigned short*)&vl[2])[e], ((const unsigned short*)&vl[3])[e] };
      ushort4 td = { ((const unsigned short*)&vl[4])[e], ((const unsigned short*)&vl[5])[e],
                     ((const unsigned short*)&vl[6])[e], ((const unsigned short*)&vl[7])[e] };
      *(ushort4*)&VtH[(vd4+e)*VS + vr0]     = ta;
      *(ushort4*)&VtH[(vd4+e)*VS + vr0 + 4] = tb;
      *(ushort4*)&VtL[(vd4+e)*VS + vr0]     = tc;
      *(ushort4*)&VtL[(vd4+e)*VS + vr0 + 4] = td;
    }
  }
  __syncthreads();

  float m_run[4] = {-3.0e38f, -3.0e38f, -3.0e38f, -3.0e38f};
  float l_run[4] = {0.f, 0.f, 0.f, 0.f};
  f32x4 accO[8] = {};
  f32x4 accB0 = {}, accB1 = {}, accB2 = {};   // pe-term band (accB2 carried)

  for (int kt = 0; kt < NKT; ++kt) {
    const int k0 = kt * KT;
    const int base_w = k0 - q0w + 497;

    // ---- A) prefetch K-hi/V tile kt+1 into registers ----
    uint4 kxh[4];
    ushort4 vxh[8], vxl[8];
    const bool pf = kt < NKT-1;
    if (pf) {
      size_t krow = (size_t)(b*LL + k0 + KT + kr)*DM + (size_t)n*HD + ks;
#pragma unroll
      for (int i = 0; i < 4; ++i)
        kxh[i] = *(const uint4*)&khp[krow + i*8];
#pragma unroll
      for (int i = 0; i < 8; ++i) {
        size_t vrow = (size_t)(b*LL + k0 + KT + vr0 + i)*DM + n*HD + vd4;
        vxh[i] = *(const ushort4*)&vhp[vrow];
        vxl[i] = *(const ushort4*)&vlp[vrow];
      }
    }

    // ---- B) compute tile kt ----
    float d2v1, d2v2;
    {
      int di1 = base_w + 16 + lm; di1 = di1 > PEN-1 ? PEN-1 : di1;
      int di2 = base_w + 32 + lm; di2 = di2 > PEN-1 ? PEN-1 : di2;
      d2v1 = d2p[n*PEN + di1];
      d2v2 = d2p[n*PEN + di2];
    }
    const int msk0 = mask[b*LL + k0 + lm];
    const int msk1 = mask[b*LL + k0 + 16 + lm];

    // K-lo B-frags straight from global/L2 (issued early; consumed in the
    // reordered 3rd AC pass below, after ~16 covering MFMAs)
    bf16x8 klo_f[2][4];
#pragma unroll
    for (int tt = 0; tt < 2; ++tt)
#pragma unroll
      for (int c = 0; c < 4; ++c)
        klo_f[tt][c] = *(const bf16x8*)&klp[(size_t)(b*LL + k0 + tt*16 + lm)*DM + n*HD + c*32 + lg*8];

    // pe B-frag loads for the two NEW band rows (jt=1,2)
    bf16x8 p1h[4], p1l[4], p2h[4], p2l[4];
    {
      int pr1 = base_w + 16 + lm; pr1 = pr1 > PEN-1 ? PEN-1 : pr1;
      int pr2 = base_w + 32 + lm; pr2 = pr2 > PEN-1 ? PEN-1 : pr2;
      const unsigned short* pb1 = pehp + (size_t)pr1*HD + lg*8;
      const unsigned short* pq1 = pelp + (size_t)pr1*HD + lg*8;
      const unsigned short* pb2 = pehp + (size_t)pr2*HD + lg*8;
      const unsigned short* pq2 = pelp + (size_t)pr2*HD + lg*8;
#pragma unroll
      for (int c = 0; c < 4; ++c) {
        p1h[c] = *(const bf16x8*)(pb1 + c*32);
        p1l[c] = *(const bf16x8*)(pq1 + c*32);
        p2h[c] = *(const bf16x8*)(pb2 + c*32);
        p2l[c] = *(const bf16x8*)(pq2 + c*32);
      }
    }

    __builtin_amdgcn_s_setprio(1);
    // AC hi passes (qah*Kh + qal*Kh) from LDS -- cover the klo/pe loads
    f32x4 accA[2] = {};
#pragma unroll
    for (int tt = 0; tt < 2; ++tt)
#pragma unroll
      for (int c = 0; c < 4; ++c) {
        const int krw = tt*16 + lm;
        bf16x8 kfh = *(const bf16x8*)&KsH[krw*136 + (c*4+lg)*8];
        accA[tt] = __builtin_amdgcn_mfma_f32_16x16x32_bf16(qah[c], kfh, accA[tt], 0, 0, 0);
        accA[tt] = __builtin_amdgcn_mfma_f32_16x16x32_bf16(qal[c], kfh, accA[tt], 0, 0, 0);
      }

    // pe-term MFMA (3-pass); accB0 carried (first tile computed fresh)
    if (kt == 0) {
      int pr0 = base_w + lm; pr0 = pr0 < 0 ? 0 : (pr0 > PEN-1 ? PEN-1 : pr0);
      const unsigned short* pb0 = pehp + (size_t)pr0*HD + lg*8;
      const unsigned short* pq0 = pelp + (size_t)pr0*HD + lg*8;
      f32x4 a = {};
#pragma unroll
      for (int c = 0; c < 4; ++c) {
        bf16x8 ph = *(const bf16x8*)(pb0 + c*32);
        bf16x8 pl = *(const bf16x8*)(pq0 + c*32);
        a = __builtin_amdgcn_mfma_f32_16x16x32_bf16(qah[c], ph, a, 0, 0, 0);
        a = __builtin_amdgcn_mfma_f32_16x16x32_bf16(qah[c], pl, a, 0, 0, 0);
        a = __builtin_amdgcn_mfma_f32_16x16x32_bf16(qal[c], ph, a, 0, 0, 0);
      }
      float dv0 = d2p[n*PEN + pr0];
#pragma unroll
      for (int r = 0; r < 4; ++r) a[r] += dv0;
      accB0 = a;
    } else {
      accB0 = accB2;
    }
    {
      f32x4 a = {};
#pragma unroll
      for (int c = 0; c < 4; ++c) {
        a = __builtin_amdgcn_mfma_f32_16x16x32_bf16(qah[c], p1h[c], a, 0, 0, 0);
        a = __builtin_amdgcn_mfma_f32_16x16x32_bf16(qah[c], p1l[c], a, 0, 0, 0);
        a = __builtin_amdgcn_mfma_f32_16x16x32_bf16(qal[c], p1h[c], a, 0, 0, 0);
      }
#pragma unroll
      for (int r = 0; r < 4; ++r) a[r] += d2v1;
      accB1 = a;
    }
    {
      f32x4 a = {};
#pragma unroll
      for (int c = 0; c < 4; ++c) {
        a = __builtin_amdgcn_mfma_f32_16x16x32_bf16(qah[c], p2h[c], a, 0, 0, 0);
        a = __builtin_amdgcn_mfma_f32_16x16x32_bf16(qah[c], p2l[c], a, 0, 0, 0);
        a = __builtin_amdgcn_mfma_f32_16x16x32_bf16(qal[c], p2h[c], a, 0, 0, 0);
      }
#pragma unroll
      for (int r = 0; r < 4; ++r) a[r] += d2v2;
      accB2 = a;
    }

    // AC lo pass (qah * K-lo from global)
#pragma unroll
    for (int tt = 0; tt < 2; ++tt)
#pragma unroll
      for (int c = 0; c < 4; ++c)
        accA[tt] = __builtin_amdgcn_mfma_f32_16x16x32_bf16(qah[c], klo_f[tt][c], accA[tt], 0, 0, 0);
    __builtin_amdgcn_s_setprio(0);

    // ---- shift-gather pe-term via in-wave shuffle (no LDS) ----
    float s[2][4];
#pragma unroll
    for (int r = 0; r < 4; ++r) {
      const int qi = lg*4 + r;
      const int jm = (lm - qi + 15) & 15;
      const int src = (l & 48) | jm;
      const bool carry = lm > qi;
      float sh0 = __shfl(accB0[r], src);
      float sh1 = __shfl(accB1[r], src);
      float sh2 = __shfl(accB2[r], src);
      float bd0 = carry ? sh1 : sh0;
      float bd1 = carry ? sh2 : sh1;
      float v0 = accA[0][r] + bd0;
      float v1 = accA[1][r] + bd1;
      s[0][r] = (msk0 == 0) ? -1e30f : v0;
      s[1][r] = (msk1 == 0) ? -1e30f : v1;
    }

    // ---- online softmax with exact defer-scale ----
    float mt4[4];
    int allold = 1;
#pragma unroll
    for (int r = 0; r < 4; ++r) {
      float mt = fmaxf(s[0][r], s[1][r]);
      mt = fmaxf(mt, __shfl_xor(mt, 1));
      mt = fmaxf(mt, __shfl_xor(mt, 2));
      mt = fmaxf(mt, __shfl_xor(mt, 4));
      mt = fmaxf(mt, __shfl_xor(mt, 8));
      mt4[r] = mt;
      allold &= (mt <= m_run[r]) ? 1 : 0;
    }
    if (!__all(allold)) {
#pragma unroll
      for (int r = 0; r < 4; ++r) {
        float mn = fmaxf(m_run[r], mt4[r]);
        float sc = __expf(m_run[r] - mn);
        m_run[r] = mn;
        l_run[r] *= sc;
#pragma unroll
        for (int j8 = 0; j8 < 8; ++j8) accO[j8][r] *= sc;
      }
    }
#pragma unroll
    for (int r = 0; r < 4; ++r) {
      float p0 = __expf(s[0][r] - m_run[r]);
      float p1 = __expf(s[1][r] - m_run[r]);
      s[0][r] = p0; s[1][r] = p1;
      float la = p0 + p1;
      la += __shfl_xor(la, 1);
      la += __shfl_xor(la, 2);
      la += __shfl_xor(la, 4);
      la += __shfl_xor(la, 8);
      l_run[r] += la;
    }

    // P -> split bf16 in LDS (trunc hi / RNE lo; A-frag layout).
#pragma unroll
    for (int tt = 0; tt < 2; ++tt)
#pragma unroll
      for (int r = 0; r < 4; ++r) {
        int qi = lg*4 + r, kc = tt*16 + lm;
        float p = s[tt][r];
        unsigned u = __float_as_uint(p);
        PsH[w][qi*40 + kc] = (unsigned short)(u >> 16);
        PsL[w][qi*40 + kc] = f2b(p - __uint_as_float(u & 0xffff0000u));
      }

    // PV MFMA (3-pass)
    {
      __builtin_amdgcn_s_setprio(1);
      bf16x8 pah = *(const bf16x8*)&PsH[w][lm*40 + lg*8];
      bf16x8 pal = *(const bf16x8*)&PsL[w][lm*40 + lg*8];
#pragma unroll
      for (int j8 = 0; j8 < 8; ++j8) {
        const int dim = j8*16 + lm;
        bf16x8 vfh = *(const bf16x8*)&VtH[dim*VS + lg*8];
        bf16x8 vfl = *(const bf16x8*)&VtL[dim*VS + lg*8];
        accO[j8] = __builtin_amdgcn_mfma_f32_16x16x32_bf16(pah, vfh, accO[j8], 0, 0, 0);
        accO[j8] = __builtin_amdgcn_mfma_f32_16x16x32_bf16(pah, vfl, accO[j8], 0, 0, 0);
        accO[j8] = __builtin_amdgcn_mfma_f32_16x16x32_bf16(pal, vfh, accO[j8], 0, 0, 0);
      }
      __builtin_amdgcn_s_setprio(0);
    }

    __syncthreads();   // both waves done reading KsH/Vt

    // ---- C) write staged tile kt+1 ----
    if (pf) {
#pragma unroll
      for (int i = 0; i < 4; ++i)
        *(uint4*)&KsH[kr*136 + ks + i*8] = kxh[i];
#pragma unroll
      for (int e = 0; e < 4; ++e) {
        ushort4 ta = { ((const unsigned short*)&vxh[0])[e], ((const unsigned short*)&vxh[1])[e],
                       ((const unsigned short*)&vxh[2])[e], ((const unsigned short*)&vxh[3])[e] };
        ushort4 tb = { ((const unsigned short*)&vxh[4])[e], ((const unsigned short*)&vxh[5])[e],
                       ((const unsigned short*)&vxh[6])[e], ((const unsigned short*)&vxh[7])[e] };
        ushort4 tc = { ((const unsigned short*)&vxl[0])[e], ((const unsigned short*)&vxl[1])[e],
                       ((const unsigned short*)&vxl[2])[e], ((const unsigned short*)&vxl[3])[e] };
        ushort4 td = { ((const unsigned short*)&vxl[4])[e], ((const unsigned short*)&vxl[5])[e],
                       ((const unsigned short*)&vxl[6])[e], ((const unsigned short*)&vxl[7])[e] };
        *(ushort4*)&VtH[(vd4+e)*VS + vr0]     = ta;
        *(ushort4*)&VtH[(vd4+e)*VS + vr0 + 4] = tb;
        *(ushort4*)&VtL[(vd4+e)*VS + vr0]     = tc;
        *(ushort4*)&VtL[(vd4+e)*VS + vr0 + 4] = td;
      }
    }
    __syncthreads();
  }

  // ---- epilogue: O / l  ->  qbuf ----
  float inv[4];
#pragma unroll
  for (int r = 0; r < 4; ++r) inv[r] = 1.0f / l_run[r];
#pragma unroll
  for (int j8 = 0; j8 < 8; ++j8)
#pragma unroll
    for (int r = 0; r < 4; ++r)
      outp[(size_t)(b*LL + q0w + lg*4 + r)*DM + n*HD + j8*16 + lm] = accO[j8][r] * inv[r];
}

// ------- residual add + layernorm (+ split hi/lo bf16 for next GEMM) -------
__global__ __launch_bounds__(256) void add_ln_kernel(
    const float* __restrict__ y, int ys,
    const float* __restrict__ res,
    const float* __restrict__ g, const float* __restrict__ bt,
    float* __restrict__ out,
    unsigned short* __restrict__ ohi, unsigned short* __restrict__ olo)
{
  const int r = blockIdx.x, t = threadIdx.x;
  float4 v = *(const float4*)&y[(size_t)r*ys + t*4];
  float4 w = *(const float4*)&res[(size_t)r*DM + t*4];
  float4 s = {v.x+w.x, v.y+w.y, v.z+w.z, v.w+w.w};
  float sum = s.x + s.y + s.z + s.w;
  float ssq = s.x*s.x + s.y*s.y + s.z*s.z + s.w*s.w;
#pragma unroll
  for (int off = 32; off >= 1; off >>= 1) {
    sum += __shfl_down(sum, off);
    ssq += __shfl_down(ssq, off);
  }
  __shared__ float red[8];
  int wid = t >> 6;
  if ((t & 63) == 0) { red[wid] = sum; red[wid+4] = ssq; }
  __syncthreads();
  float totS = red[0] + red[1] + red[2] + red[3];
  float totQ = red[4] + red[5] + red[6] + red[7];
  float mu  = totS * (1.0f/DM);
  float var = totQ * (1.0f/DM) - mu*mu;
  float inv = rsqrtf(var + 1e-5f);
  float4 gg = *(const float4*)&g[t*4];
  float4 bb = *(const float4*)&bt[t*4];
  float4 o;
  o.x = (s.x - mu)*inv*gg.x + bb.x;
  o.y = (s.y - mu)*inv*gg.y + bb.y;
  o.z = (s.z - mu)*inv*gg.z + bb.z;
  o.w = (s.w - mu)*inv*gg.w + bb.w;
  *(float4*)&out[(size_t)r*DM + t*4] = o;
  float xs[4] = {o.x, o.y, o.z, o.w};
  ushort4 h4, l4;
  unsigned short* hp = (unsigned short*)&h4;
  unsigned short* lp = (unsigned short*)&l4;
#pragma unroll
  for (int e = 0; e < 4; ++e) {
    unsigned short h = f2b(xs[e]);
    hp[e] = h;
    lp[e] = f2b(xs[e] - b2f(h));
  }
  *(ushort4*)&ohi[(size_t)r*DM + t*4] = h4;
  *(ushort4*)&olo[(size_t)r*DM + t*4] = l4;
}

extern "C" void kernel_launch(void* const* d_in, const int* in_sizes, int n_in,
                              void* d_out, int out_size, void* d_ws, size_t ws_size,
                              hipStream_t stream) {
  const float* x    = (const float*)d_in[0];
  const int*   mask = (const int*)d_in[1];
  const float* qv_w = (const float*)d_in[2];
  const float* rrb  = (const float*)d_in[3];
  const float* rwb  = (const float*)d_in[4];
  const float* ln1g = (const float*)d_in[5];
  const float* ln1b = (const float*)d_in[6];
  const float* ffnw = (const float*)d_in[7];
  const float* ffnb = (const float*)d_in[8];
  const float* ln2g = (const float*)d_in[9];
  const float* ln2b = (const float*)d_in[10];

  float* h  = (float*)d_out;                      // [MM][DM] hidden (f32)
  unsigned short* peh = (unsigned short*)d_ws;    // 262144 sh (hi+lo)
  unsigned short* pel = peh + (size_t)PEN*HD;
  float* d2   = (float*)(pel + (size_t)PEN*HD);   // 8192 f32
  float* qbuf = d2 + (size_t)NH*PEN;              // MM*DM f32 (16.8 MB)
  unsigned short* vhi = (unsigned short*)(qbuf + (size_t)MM*DM);  // MM*DM
  unsigned short* vlo = vhi + (size_t)MM*DM;                      // MM*DM
  unsigned short* hhi = vlo + (size_t)MM*DM;                      // MM*DM
  unsigned short* hlo = hhi + (size_t)MM*DM;                      // MM*DM
  // total = 50,888,704 bytes (proven layout size)

  hipMemcpyAsync(h, x, (size_t)MM*DM*sizeof(float), hipMemcpyDeviceToDevice, stream);
  split_kernel<<<(MM*DM)/1024, 256, 0, stream>>>(x, hhi, hlo, MM*DM);
  pe_kernel<<<(PEN*HD)/256, 256, 0, stream>>>(peh, pel);

  for (int l = 0; l < NL; ++l) {
    const float* rr_l = rrb + (size_t)l*NH*HD;
    const float* rw_l = rwb + (size_t)l*NH*HD;
    d2_kernel<<<(NH*PEN)/256, 256, 0, stream>>>(rr_l, rw_l, peh, pel, d2);
    // q (f32 -> qbuf) | v (split bf16 -> vhi/vlo) = h @ qv_w^T
    gemm_mfma<false><<<dim3((2*DM)/128, MM/128), 256, 0, stream>>>(
        hhi, hlo, qv_w + (size_t)l*2*DM*DM, nullptr, qbuf, vhi, vlo, 2*DM, DM, DM);
    // fused relative attention -> qbuf
    attn_mfma<<<dim3(NH, LL/QT, BB), 128, 0, stream>>>(
        qbuf, hhi, hlo, vhi, vlo, peh, pel, rr_l, mask, d2, qbuf);
    // h = LN1(attn + h), + split
    add_ln_kernel<<<MM, 256, 0, stream>>>(qbuf, DM, h,
        ln1g + (size_t)l*DM, ln1b + (size_t)l*DM, h, hhi, hlo);
    // ffn out (f32) = relu(h @ ffn_w^T + b) -> qbuf
    gemm_mfma<true><<<dim3(DM/128, MM/128), 256, 0, stream>>>(
        hhi, hlo, ffnw + (size_t)l*DM*DM, ffnb + (size_t)l*DM, qbuf, nullptr, nullptr, DM, DM, DM);
    // h = LN2(ffn + h), + split
    add_ln_kernel<<<MM, 256, 0, stream>>>(qbuf, DM, h,
        ln2g + (size_t)l*DM, ln2b + (size_t)l*DM, h, hhi, hlo);
  }
  (void)in_sizes; (void)n_in; (void)out_size; (void)ws_size;
}

// Round 15
// 913.735 us; speedup vs baseline: 1.2481x; 1.2481x over previous
//
#include <hip/hip_runtime.h>
#include <math.h>

#define NL 4
#define DM 1024
#define NH 8
#define HD 128
#define BB 8
#define LL 512
#define MM (BB*LL)      // 4096 rows
#define PEN (2*LL)      // 1024 pe rows
#define QT 64           // q rows per attn block
#define KT 32           // k tile
#define NKT (LL/KT)     // 16
#define VS 44           // Vt LDS row stride (shorts)

typedef __attribute__((ext_vector_type(8))) __bf16 bf16x8;
typedef __attribute__((ext_vector_type(4))) float f32x4;

// ---------------- helpers ----------------
__device__ __forceinline__ unsigned short f2b(float f) {   // RNE f32->bf16
  unsigned int u = __float_as_uint(f);
  u = (u + 0x7FFFu + ((u >> 16) & 1u)) >> 16;
  return (unsigned short)u;
}
__device__ __forceinline__ float b2f(unsigned short s) {
  return __uint_as_float(((unsigned int)s) << 16);
}
__device__ __forceinline__ void glds16(const void* g, void* l) {
  __builtin_amdgcn_global_load_lds(
      (const __attribute__((address_space(1))) unsigned int*)g,
      (__attribute__((address_space(3))) unsigned int*)l, 16, 0, 0);
}
union U8 { unsigned short s[8]; bf16x8 v; };
// trunc-hi / RNE-lo split of 8 floats
__device__ __forceinline__ void split8(const float4& a, const float4& b,
                                       bf16x8& h, bf16x8& l) {
  float x[8] = {a.x,a.y,a.z,a.w,b.x,b.y,b.z,b.w};
  U8 uh, ul;
#pragma unroll
  for (int e = 0; e < 8; ++e) {
    unsigned u = __float_as_uint(x[e]);
    uh.s[e] = (unsigned short)(u >> 16);
    ul.s[e] = f2b(x[e] - __uint_as_float(u & 0xffff0000u));
  }
  h = uh.v; l = ul.v;
}

// -------- relative position embedding (RNE hi + RNE residual lo) ----------
__global__ __launch_bounds__(256) void pe_kernel(unsigned short* __restrict__ peh,
                                                 unsigned short* __restrict__ pel) {
  int idx = blockIdx.x * 256 + threadIdx.x;
  if (idx >= PEN * HD) return;
  int p = idx / HD, j = idx % HD;
  int tt = (j < 64) ? j : (j - 64);
  float invf = expf((float)tt * (-9.210340371976184f / 63.0f));
  float ang = (float)(p - LL) * invf;
  float v = (j < 64) ? sinf(ang) : cosf(ang);
  unsigned short h = f2b(v);
  peh[idx] = h;
  pel[idx] = f2b(v - b2f(h));
}

// ---------------- d2[n][p] = (rw[n]-rr[n]) . pe[p] ----------------
__global__ __launch_bounds__(256) void d2_kernel(const float* __restrict__ rrb,
                                                 const float* __restrict__ rwb,
                                                 const unsigned short* __restrict__ peh,
                                                 const unsigned short* __restrict__ pel,
                                                 float* __restrict__ d2) {
  int idx = blockIdx.x * 256 + threadIdx.x;
  if (idx >= NH * PEN) return;
  int n = idx / PEN, p = idx % PEN;
  float s = 0.f;
  for (int d = 0; d < HD; ++d) {
    float pv = b2f(peh[p*HD + d]) + b2f(pel[p*HD + d]);
    s += (rwb[n*HD + d] - rrb[n*HD + d]) * pv;
  }
  d2[idx] = s;
}

// ---------------- split f32 -> (hi,lo) bf16 pair, RNE ----------------
__global__ __launch_bounds__(256) void split_kernel(const float* __restrict__ in,
                                                    unsigned short* __restrict__ hi,
                                                    unsigned short* __restrict__ lo,
                                                    int n) {
  int i = (blockIdx.x * 256 + threadIdx.x) * 4;
  if (i >= n) return;
  float4 v = *(const float4*)&in[i];
  float x[4] = {v.x, v.y, v.z, v.w};
  ushort4 h4, l4;
  unsigned short* hp = (unsigned short*)&h4;
  unsigned short* lp = (unsigned short*)&l4;
#pragma unroll
  for (int e = 0; e < 4; ++e) {
    unsigned short h = f2b(x[e]);
    hp[e] = h;
    lp[e] = f2b(x[e] - b2f(h));
  }
  *(ushort4*)&hi[i] = h4;
  *(ushort4*)&lo[i] = l4;
}

// ---------------- split-bf16 MFMA GEMM: C = A[M][K] @ Bw[N][K]^T -----------
// BK=64, A via global_load_lds (linear dest + source-seg swizzle), B
// reg-staged pad 72. XCD-chunked block swizzle. FFN=false: columns <DM go
// f32 to C (ldc=DM); columns >=DM are split into Vhi/Vlo. FFN=true: f32 +
// bias + relu to C.
template<bool FFN>
__global__ __launch_bounds__(256) void gemm_mfma(
    const unsigned short* __restrict__ Ah, const unsigned short* __restrict__ Al,
    const float* __restrict__ Bw, const float* __restrict__ bias,
    float* __restrict__ C, unsigned short* __restrict__ Vhi,
    unsigned short* __restrict__ Vlo, int N, int K, int ldc) {
  __shared__ __align__(16) unsigned short AsH[128*64];
  __shared__ __align__(16) unsigned short AsL[128*64];
  __shared__ __align__(16) unsigned short BsH[128*72];
  __shared__ __align__(16) unsigned short BsL[128*72];
  const int t = threadIdx.x;
  const int w = t >> 6, l = t & 63;
  const int gx = gridDim.x;
  const int nwg = gx * gridDim.y;
  const int id = blockIdx.y * gx + blockIdx.x;
  const int swz = (id & 7) * (nwg >> 3) + (id >> 3);
  const int bm = (swz / gx) * 128, bn = (swz % gx) * 128;
  const int wr = (w >> 1) * 64, wc = (w & 1) * 64;

  const int aseg = ((t & 7) ^ ((t >> 3) & 7)) * 8;
  const unsigned short* Ahb = Ah + (size_t)(bm + (t >> 3)) * K + aseg;
  const unsigned short* Alb = Al + (size_t)(bm + (t >> 3)) * K + aseg;

  const int brow = t >> 1, bhalf = (t & 1) * 32;
  const float* Bb = Bw + (size_t)(bn + brow) * K + bhalf;

  f32x4 acc[4][4] = {};
  const int lm = l & 15;
  const int lg = l >> 4;

  for (int k0 = 0; k0 < K; k0 += 64) {
    float4 bv[8];
#pragma unroll
    for (int c = 0; c < 8; ++c)
      bv[c] = *(const float4*)(Bb + k0 + c*4);
#pragma unroll
    for (int i = 0; i < 4; ++i) {
      glds16(Ahb + (size_t)(i*32)*K + k0, &AsH[w*512 + i*2048]);
      glds16(Alb + (size_t)(i*32)*K + k0, &AsL[w*512 + i*2048]);
    }
#pragma unroll
    for (int c = 0; c < 8; ++c) {
      float xs[4] = {bv[c].x, bv[c].y, bv[c].z, bv[c].w};
      ushort4 h4, l4;
      unsigned short* hp = (unsigned short*)&h4;
      unsigned short* lp = (unsigned short*)&l4;
#pragma unroll
      for (int e = 0; e < 4; ++e) {
        unsigned u = __float_as_uint(xs[e]);
        hp[e] = (unsigned short)(u >> 16);
        float r = xs[e] - __uint_as_float(u & 0xffff0000u);
        lp[e] = (unsigned short)(__float_as_uint(r) >> 16);
      }
      *(ushort4*)&BsH[brow*72 + bhalf + c*4] = h4;
      *(ushort4*)&BsL[brow*72 + bhalf + c*4] = l4;
    }
    __syncthreads();

#pragma unroll
    for (int kk = 0; kk < 2; ++kk) {
      bf16x8 afh[4], afl[4], bfh[4], bfl[4];
#pragma unroll
      for (int i = 0; i < 4; ++i) {
        const int row = wr + i*16 + lm;
        const int sw = ((kk*4 + lg) ^ (lm & 7)) * 8;
        afh[i] = *(const bf16x8*)&AsH[row*64 + sw];
        afl[i] = *(const bf16x8*)&AsL[row*64 + sw];
      }
#pragma unroll
      for (int j = 0; j < 4; ++j) {
        bfh[j] = *(const bf16x8*)&BsH[(wc + j*16 + lm)*72 + kk*32 + lg*8];
        bfl[j] = *(const bf16x8*)&BsL[(wc + j*16 + lm)*72 + kk*32 + lg*8];
      }
#pragma unroll
      for (int i = 0; i < 4; ++i)
#pragma unroll
        for (int j = 0; j < 4; ++j) {
          acc[i][j] = __builtin_amdgcn_mfma_f32_16x16x32_bf16(afh[i], bfh[j], acc[i][j], 0, 0, 0);
          acc[i][j] = __builtin_amdgcn_mfma_f32_16x16x32_bf16(afh[i], bfl[j], acc[i][j], 0, 0, 0);
          acc[i][j] = __builtin_amdgcn_mfma_f32_16x16x32_bf16(afl[i], bfh[j], acc[i][j], 0, 0, 0);
        }
    }
    __syncthreads();
  }

  const int cr = (l >> 4) * 4;
  const bool vhalf = (!FFN) && (bn >= DM);   // block-uniform
#pragma unroll
  for (int i = 0; i < 4; ++i) {
#pragma unroll
    for (int j = 0; j < 4; ++j) {
      int row = bm + wr + i*16 + cr;
      int col = bn + wc + j*16 + lm;
      float bvl = FFN ? bias[col] : 0.f;
      f32x4 a = acc[i][j];
#pragma unroll
      for (int r4 = 0; r4 < 4; ++r4) {
        float v = a[r4];
        if (FFN) {
          v = fmaxf(v + bvl, 0.f);
          C[(size_t)(row + r4) * ldc + col] = v;
        } else if (vhalf) {
          unsigned u = __float_as_uint(v);
          size_t off = (size_t)(row + r4) * DM + (col - DM);
          Vhi[off] = (unsigned short)(u >> 16);
          Vlo[off] = f2b(v - __uint_as_float(u & 0xffff0000u));
        } else {
          C[(size_t)(row + r4) * ldc + col] = v;
        }
      }
    }
  }
}

// ================= MFMA fused relative attention (v10, best-known) ========
// Round-13 configuration: QT=64, 4 waves, grid (8,8,8) with XCD role
// remap (n = id&7), pe band-carry + hoisted pe loads, shfl shift-gather,
// exact defer-scale, setprio around MFMA clusters, 49KB LDS, (256,2).
__global__ __launch_bounds__(256, 2) void attn_mfma(
    const float* __restrict__ qbuf,         // [MM][1024] f32 q (also output)
    const unsigned short* __restrict__ khp, // keys hi  [MM][1024]
    const unsigned short* __restrict__ klp, // keys lo
    const unsigned short* __restrict__ vhp, // v hi [MM][1024]
    const unsigned short* __restrict__ vlp, // v lo
    const unsigned short* __restrict__ pehp,// [1024][128] bf16 hi
    const unsigned short* __restrict__ pelp,// [1024][128] bf16 lo
    const float* __restrict__ rrb,          // [NH][128] layer slice
    const int*   __restrict__ mask,         // [BB][LL]
    const float* __restrict__ d2p,          // [NH][1024]
    float* __restrict__ outp)               // = qbuf (stride 1024)
{
  __shared__ __align__(16) unsigned short KsH[KT*136];   // 8.5 KB
  __shared__ __align__(16) unsigned short KsL[KT*136];
  __shared__ __align__(16) unsigned short VtH[HD*VS];    // 11 KB
  __shared__ __align__(16) unsigned short VtL[HD*VS];
  __shared__ __align__(16) unsigned short PsH[4][16*40]; // 5 KB
  __shared__ __align__(16) unsigned short PsL[4][16*40];
  // total ~49 KB

  const int id = blockIdx.x + 8*blockIdx.y + 64*blockIdx.z;
  const int n  = id & 7;            // XCD key: same (n,b) group -> same id%8
  const int qt = (id >> 3) & 7;
  const int b  = id >> 6;
  const int q0 = qt * QT;
  const int t  = threadIdx.x;
  const int w  = t >> 6, l = t & 63;
  const int lm = l & 15, lg = l >> 4;
  const int q0w = q0 + w*16;
  const int r8 = t >> 3, s8 = t & 7;        // K staging: row, 16-short seg
  const int vr0 = t >> 5, vd4 = (t & 31)*4; // V staging: row block, dim

  // ---- qa A-frags in registers (split hi/lo) ----
  bf16x8 qah[4], qal[4];
  {
    size_t qrow = (size_t)(b*LL + q0w + lm) * DM + (size_t)n*HD;
#pragma unroll
    for (int c = 0; c < 4; ++c) {
      int d0 = c*32 + lg*8;
      float4 x1 = *(const float4*)&qbuf[qrow + d0];
      float4 x2 = *(const float4*)&qbuf[qrow + d0 + 4];
      float4 r1 = *(const float4*)&rrb[n*HD + d0];
      float4 r2 = *(const float4*)&rrb[n*HD + d0 + 4];
      float4 a = {x1.x+r1.x, x1.y+r1.y, x1.z+r1.z, x1.w+r1.w};
      float4 bq = {x2.x+r2.x, x2.y+r2.y, x2.z+r2.z, x2.w+r2.w};
      split8(a, bq, qah[c], qal[c]);
    }
  }

  // ---- prologue staging: K/V tile 0 ----
  {
    size_t krow = (size_t)(b*LL + r8)*DM + (size_t)n*HD + s8*16;
    *(uint4*)&KsH[r8*136 + s8*16]     = *(const uint4*)&khp[krow];
    *(uint4*)&KsH[r8*136 + s8*16 + 8] = *(const uint4*)&khp[krow + 8];
    *(uint4*)&KsL[r8*136 + s8*16]     = *(const uint4*)&klp[krow];
    *(uint4*)&KsL[r8*136 + s8*16 + 8] = *(const uint4*)&klp[krow + 8];
    ushort4 vh[4], vl[4];
#pragma unroll
    for (int i = 0; i < 4; ++i) {
      size_t vrow = (size_t)(b*LL + vr0*4 + i)*DM + n*HD + vd4;
      vh[i] = *(const ushort4*)&vhp[vrow];
      vl[i] = *(const ushort4*)&vlp[vrow];
    }
#pragma unroll
    for (int e = 0; e < 4; ++e) {
      ushort4 th = { ((const unsigned short*)&vh[0])[e], ((const unsigned short*)&vh[1])[e],
                     ((const unsigned short*)&vh[2])[e], ((const unsigned short*)&vh[3])[e] };
      ushort4 tl = { ((const unsigned short*)&vl[0])[e], ((const unsigned short*)&vl[1])[e],
                     ((const unsigned short*)&vl[2])[e], ((const unsigned short*)&vl[3])[e] };
      *(ushort4*)&VtH[(vd4+e)*VS + vr0*4] = th;
      *(ushort4*)&VtL[(vd4+e)*VS + vr0*4] = tl;
    }
  }
  __syncthreads();

  float m_run[4] = {-3.0e38f, -3.0e38f, -3.0e38f, -3.0e38f};
  float l_run[4] = {0.f, 0.f, 0.f, 0.f};
  f32x4 accO[8] = {};
  f32x4 accB0 = {}, accB1 = {}, accB2 = {};   // pe-term band (accB2 carried)

  for (int kt = 0; kt < NKT; ++kt) {
    const int k0 = kt * KT;
    const int base_w = k0 - q0w + 497;

    // ---- A) prefetch K/V tile kt+1 into registers ----
    uint4 kxh0, kxh1, kxl0, kxl1;
    ushort4 vxh[4], vxl[4];
    const bool pf = kt < NKT-1;
    if (pf) {
      size_t krow = (size_t)(b*LL + k0 + KT + r8)*DM + (size_t)n*HD + s8*16;
      kxh0 = *(const uint4*)&khp[krow];     kxh1 = *(const uint4*)&khp[krow + 8];
      kxl0 = *(const uint4*)&klp[krow];     kxl1 = *(const uint4*)&klp[krow + 8];
#pragma unroll
      for (int i = 0; i < 4; ++i) {
        size_t vrow = (size_t)(b*LL + k0 + KT + vr0*4 + i)*DM + n*HD + vd4;
        vxh[i] = *(const ushort4*)&vhp[vrow];
        vxl[i] = *(const ushort4*)&vlp[vrow];
      }
    }

    // ---- B) compute tile kt ----
    float d2v1, d2v2;
    {
      int di1 = base_w + 16 + lm; di1 = di1 > PEN-1 ? PEN-1 : di1;
      int di2 = base_w + 32 + lm; di2 = di2 > PEN-1 ? PEN-1 : di2;
      d2v1 = d2p[n*PEN + di1];
      d2v2 = d2p[n*PEN + di2];
    }
    const int msk0 = mask[b*LL + k0 + lm];
    const int msk1 = mask[b*LL + k0 + 16 + lm];

    // pe B-frag loads for the two NEW band rows (jt=1,2) -- before AC
    bf16x8 p1h[4], p1l[4], p2h[4], p2l[4];
    {
      int pr1 = base_w + 16 + lm; pr1 = pr1 > PEN-1 ? PEN-1 : pr1;
      int pr2 = base_w + 32 + lm; pr2 = pr2 > PEN-1 ? PEN-1 : pr2;
      const unsigned short* pb1 = pehp + (size_t)pr1*HD + lg*8;
      const unsigned short* pq1 = pelp + (size_t)pr1*HD + lg*8;
      const unsigned short* pb2 = pehp + (size_t)pr2*HD + lg*8;
      const unsigned short* pq2 = pelp + (size_t)pr2*HD + lg*8;
#pragma unroll
      for (int c = 0; c < 4; ++c) {
        p1h[c] = *(const bf16x8*)(pb1 + c*32);
        p1l[c] = *(const bf16x8*)(pq1 + c*32);
        p2h[c] = *(const bf16x8*)(pb2 + c*32);
        p2l[c] = *(const bf16x8*)(pq2 + c*32);
      }
    }

    // AC MFMA (3-pass, full precision)
    __builtin_amdgcn_s_setprio(1);
    f32x4 accA[2] = {};
#pragma unroll
    for (int tt = 0; tt < 2; ++tt)
#pragma unroll
      for (int c = 0; c < 4; ++c) {
        const int krow = tt*16 + lm;
        bf16x8 kfh = *(const bf16x8*)&KsH[krow*136 + (c*4+lg)*8];
        bf16x8 kfl = *(const bf16x8*)&KsL[krow*136 + (c*4+lg)*8];
        accA[tt] = __builtin_amdgcn_mfma_f32_16x16x32_bf16(qah[c], kfh, accA[tt], 0, 0, 0);
        accA[tt] = __builtin_amdgcn_mfma_f32_16x16x32_bf16(qah[c], kfl, accA[tt], 0, 0, 0);
        accA[tt] = __builtin_amdgcn_mfma_f32_16x16x32_bf16(qal[c], kfh, accA[tt], 0, 0, 0);
      }

    // pe-term MFMA (3-pass); accB0 carried (first tile computed fresh)
    if (kt == 0) {
      int pr0 = base_w + lm; pr0 = pr0 > PEN-1 ? PEN-1 : pr0;
      const unsigned short* pb0 = pehp + (size_t)pr0*HD + lg*8;
      const unsigned short* pq0 = pelp + (size_t)pr0*HD + lg*8;
      f32x4 a = {};
#pragma unroll
      for (int c = 0; c < 4; ++c) {
        bf16x8 ph = *(const bf16x8*)(pb0 + c*32);
        bf16x8 pl = *(const bf16x8*)(pq0 + c*32);
        a = __builtin_amdgcn_mfma_f32_16x16x32_bf16(qah[c], ph, a, 0, 0, 0);
        a = __builtin_amdgcn_mfma_f32_16x16x32_bf16(qah[c], pl, a, 0, 0, 0);
        a = __builtin_amdgcn_mfma_f32_16x16x32_bf16(qal[c], ph, a, 0, 0, 0);
      }
      float dv0 = d2p[n*PEN + pr0];
#pragma unroll
      for (int r = 0; r < 4; ++r) a[r] += dv0;
      accB0 = a;
    } else {
      accB0 = accB2;
    }
    {
      f32x4 a = {};
#pragma unroll
      for (int c = 0; c < 4; ++c) {
        a = __builtin_amdgcn_mfma_f32_16x16x32_bf16(qah[c], p1h[c], a, 0, 0, 0);
        a = __builtin_amdgcn_mfma_f32_16x16x32_bf16(qah[c], p1l[c], a, 0, 0, 0);
        a = __builtin_amdgcn_mfma_f32_16x16x32_bf16(qal[c], p1h[c], a, 0, 0, 0);
      }
#pragma unroll
      for (int r = 0; r < 4; ++r) a[r] += d2v1;
      accB1 = a;
    }
    {
      f32x4 a = {};
#pragma unroll
      for (int c = 0; c < 4; ++c) {
        a = __builtin_amdgcn_mfma_f32_16x16x32_bf16(qah[c], p2h[c], a, 0, 0, 0);
        a = __builtin_amdgcn_mfma_f32_16x16x32_bf16(qah[c], p2l[c], a, 0, 0, 0);
        a = __builtin_amdgcn_mfma_f32_16x16x32_bf16(qal[c], p2h[c], a, 0, 0, 0);
      }
#pragma unroll
      for (int r = 0; r < 4; ++r) a[r] += d2v2;
      accB2 = a;
    }
    __builtin_amdgcn_s_setprio(0);

    // ---- shift-gather pe-term via in-wave shuffle (no LDS) ----
    float s[2][4];
#pragma unroll
    for (int r = 0; r < 4; ++r) {
      const int qi = lg*4 + r;
      const int jm = (lm - qi + 15) & 15;
      const int src = (l & 48) | jm;
      const bool carry = lm > qi;
      float sh0 = __shfl(accB0[r], src);
      float sh1 = __shfl(accB1[r], src);
      float sh2 = __shfl(accB2[r], src);
      float bd0 = carry ? sh1 : sh0;
      float bd1 = carry ? sh2 : sh1;
      float v0 = accA[0][r] + bd0;
      float v1 = accA[1][r] + bd1;
      s[0][r] = (msk0 == 0) ? -1e30f : v0;
      s[1][r] = (msk1 == 0) ? -1e30f : v1;
    }

    // ---- online softmax with exact defer-scale ----
    float mt4[4];
    int allold = 1;
#pragma unroll
    for (int r = 0; r < 4; ++r) {
      float mt = fmaxf(s[0][r], s[1][r]);
      mt = fmaxf(mt, __shfl_xor(mt, 1));
      mt = fmaxf(mt, __shfl_xor(mt, 2));
      mt = fmaxf(mt, __shfl_xor(mt, 4));
      mt = fmaxf(mt, __shfl_xor(mt, 8));
      mt4[r] = mt;
      allold &= (mt <= m_run[r]) ? 1 : 0;
    }
    if (!__all(allold)) {
#pragma unroll
      for (int r = 0; r < 4; ++r) {
        float mn = fmaxf(m_run[r], mt4[r]);
        float sc = __expf(m_run[r] - mn);
        m_run[r] = mn;
        l_run[r] *= sc;
#pragma unroll
        for (int j8 = 0; j8 < 8; ++j8) accO[j8][r] *= sc;
      }
    }
#pragma unroll
    for (int r = 0; r < 4; ++r) {
      float p0 = __expf(s[0][r] - m_run[r]);
      float p1 = __expf(s[1][r] - m_run[r]);
      s[0][r] = p0; s[1][r] = p1;
      float la = p0 + p1;
      la += __shfl_xor(la, 1);
      la += __shfl_xor(la, 2);
      la += __shfl_xor(la, 4);
      la += __shfl_xor(la, 8);
      l_run[r] += la;
    }

    // P -> split bf16 in LDS (trunc hi / RNE lo; A-frag layout).
    // Same-wave RAW on PsH/PsL: compiler inserts the minimal lgkmcnt.
#pragma unroll
    for (int tt = 0; tt < 2; ++tt)
#pragma unroll
      for (int r = 0; r < 4; ++r) {
        int qi = lg*4 + r, kc = tt*16 + lm;
        float p = s[tt][r];
        unsigned u = __float_as_uint(p);
        PsH[w][qi*40 + kc] = (unsigned short)(u >> 16);
        PsL[w][qi*40 + kc] = f2b(p - __uint_as_float(u & 0xffff0000u));
      }

    // PV MFMA (3-pass)
    {
      __builtin_amdgcn_s_setprio(1);
      bf16x8 pah = *(const bf16x8*)&PsH[w][lm*40 + lg*8];
      bf16x8 pal = *(const bf16x8*)&PsL[w][lm*40 + lg*8];
#pragma unroll
      for (int j8 = 0; j8 < 8; ++j8) {
        const int dim = j8*16 + lm;
        bf16x8 vfh = *(const bf16x8*)&VtH[dim*VS + lg*8];
        bf16x8 vfl = *(const bf16x8*)&VtL[dim*VS + lg*8];
        accO[j8] = __builtin_amdgcn_mfma_f32_16x16x32_bf16(pah, vfh, accO[j8], 0, 0, 0);
        accO[j8] = __builtin_amdgcn_mfma_f32_16x16x32_bf16(pah, vfl, accO[j8], 0, 0, 0);
        accO[j8] = __builtin_amdgcn_mfma_f32_16x16x32_bf16(pal, vfh, accO[j8], 0, 0, 0);
      }
      __builtin_amdgcn_s_setprio(0);
    }

    __syncthreads();   // all waves done reading Ks/Vt

    // ---- C) write staged tile kt+1 ----
    if (pf) {
      *(uint4*)&KsH[r8*136 + s8*16]     = kxh0;
      *(uint4*)&KsH[r8*136 + s8*16 + 8] = kxh1;
      *(uint4*)&KsL[r8*136 + s8*16]     = kxl0;
      *(uint4*)&KsL[r8*136 + s8*16 + 8] = kxl1;
#pragma unroll
      for (int e = 0; e < 4; ++e) {
        ushort4 th = { ((const unsigned short*)&vxh[0])[e], ((const unsigned short*)&vxh[1])[e],
                       ((const unsigned short*)&vxh[2])[e], ((const unsigned short*)&vxh[3])[e] };
        ushort4 tl = { ((const unsigned short*)&vxl[0])[e], ((const unsigned short*)&vxl[1])[e],
                       ((const unsigned short*)&vxl[2])[e], ((const unsigned short*)&vxl[3])[e] };
        *(ushort4*)&VtH[(vd4+e)*VS + vr0*4] = th;
        *(ushort4*)&VtL[(vd4+e)*VS + vr0*4] = tl;
      }
    }
    __syncthreads();
  }

  // ---- epilogue: O / l  ->  qbuf ----
  float inv[4];
#pragma unroll
  for (int r = 0; r < 4; ++r) inv[r] = 1.0f / l_run[r];
#pragma unroll
  for (int j8 = 0; j8 < 8; ++j8)
#pragma unroll
    for (int r = 0; r < 4; ++r)
      outp[(size_t)(b*LL + q0w + lg*4 + r)*DM + n*HD + j8*16 + lm] = accO[j8][r] * inv[r];
}

// ------- residual add + layernorm (+ split hi/lo bf16 for next GEMM) -------
__global__ __launch_bounds__(256) void add_ln_kernel(
    const float* __restrict__ y, int ys,
    const float* __restrict__ res,
    const float* __restrict__ g, const float* __restrict__ bt,
    float* __restrict__ out,
    unsigned short* __restrict__ ohi, unsigned short* __restrict__ olo)
{
  const int r = blockIdx.x, t = threadIdx.x;
  float4 v = *(const float4*)&y[(size_t)r*ys + t*4];
  float4 w = *(const float4*)&res[(size_t)r*DM + t*4];
  float4 s = {v.x+w.x, v.y+w.y, v.z+w.z, v.w+w.w};
  float sum = s.x + s.y + s.z + s.w;
  float ssq = s.x*s.x + s.y*s.y + s.z*s.z + s.w*s.w;
#pragma unroll
  for (int off = 32; off >= 1; off >>= 1) {
    sum += __shfl_down(sum, off);
    ssq += __shfl_down(ssq, off);
  }
  __shared__ float red[8];
  int wid = t >> 6;
  if ((t & 63) == 0) { red[wid] = sum; red[wid+4] = ssq; }
  __syncthreads();
  float totS = red[0] + red[1] + red[2] + red[3];
  float totQ = red[4] + red[5] + red[6] + red[7];
  float mu  = totS * (1.0f/DM);
  float var = totQ * (1.0f/DM) - mu*mu;
  float inv = rsqrtf(var + 1e-5f);
  float4 gg = *(const float4*)&g[t*4];
  float4 bb = *(const float4*)&bt[t*4];
  float4 o;
  o.x = (s.x - mu)*inv*gg.x + bb.x;
  o.y = (s.y - mu)*inv*gg.y + bb.y;
  o.z = (s.z - mu)*inv*gg.z + bb.z;
  o.w = (s.w - mu)*inv*gg.w + bb.w;
  *(float4*)&out[(size_t)r*DM + t*4] = o;
  float xs[4] = {o.x, o.y, o.z, o.w};
  ushort4 h4, l4;
  unsigned short* hp = (unsigned short*)&h4;
  unsigned short* lp = (unsigned short*)&l4;
#pragma unroll
  for (int e = 0; e < 4; ++e) {
    unsigned short h = f2b(xs[e]);
    hp[e] = h;
    lp[e] = f2b(xs[e] - b2f(h));
  }
  *(ushort4*)&ohi[(size_t)r*DM + t*4] = h4;
  *(ushort4*)&olo[(size_t)r*DM + t*4] = l4;
}

extern "C" void kernel_launch(void* const* d_in, const int* in_sizes, int n_in,
                              void* d_out, int out_size, void* d_ws, size_t ws_size,
                              hipStream_t stream) {
  const float* x    = (const float*)d_in[0];
  const int*   mask = (const int*)d_in[1];
  const float* qv_w = (const float*)d_in[2];
  const float* rrb  = (const float*)d_in[3];
  const float* rwb  = (const float*)d_in[4];
  const float* ln1g = (const float*)d_in[5];
  const float* ln1b = (const float*)d_in[6];
  const float* ffnw = (const float*)d_in[7];
  const float* ffnb = (const float*)d_in[8];
  const float* ln2g = (const float*)d_in[9];
  const float* ln2b = (const float*)d_in[10];

  float* h  = (float*)d_out;                      // [MM][DM] hidden (f32)
  unsigned short* peh = (unsigned short*)d_ws;    // 262144 sh (hi+lo)
  unsigned short* pel = peh + (size_t)PEN*HD;
  float* d2   = (float*)(pel + (size_t)PEN*HD);   // 8192 f32
  float* qbuf = d2 + (size_t)NH*PEN;              // MM*DM f32 (16.8 MB)
  unsigned short* vhi = (unsigned short*)(qbuf + (size_t)MM*DM);  // MM*DM
  unsigned short* vlo = vhi + (size_t)MM*DM;                      // MM*DM
  unsigned short* hhi = vlo + (size_t)MM*DM;                      // MM*DM
  unsigned short* hlo = hhi + (size_t)MM*DM;                      // MM*DM
  // total = 50,888,704 bytes (proven layout size)

  hipMemcpyAsync(h, x, (size_t)MM*DM*sizeof(float), hipMemcpyDeviceToDevice, stream);
  split_kernel<<<(MM*DM)/1024, 256, 0, stream>>>(x, hhi, hlo, MM*DM);
  pe_kernel<<<(PEN*HD)/256, 256, 0, stream>>>(peh, pel);

  for (int l = 0; l < NL; ++l) {
    const float* rr_l = rrb + (size_t)l*NH*HD;
    const float* rw_l = rwb + (size_t)l*NH*HD;
    d2_kernel<<<(NH*PEN)/256, 256, 0, stream>>>(rr_l, rw_l, peh, pel, d2);
    // q (f32 -> qbuf) | v (split bf16 -> vhi/vlo) = h @ qv_w^T
    gemm_mfma<false><<<dim3((2*DM)/128, MM/128), 256, 0, stream>>>(
        hhi, hlo, qv_w + (size_t)l*2*DM*DM, nullptr, qbuf, vhi, vlo, 2*DM, DM, DM);
    // fused relative attention -> qbuf
    attn_mfma<<<dim3(LL/QT, NH, BB), 256, 0, stream>>>(
        qbuf, hhi, hlo, vhi, vlo, peh, pel, rr_l, mask, d2, qbuf);
    // h = LN1(attn + h), + split
    add_ln_kernel<<<MM, 256, 0, stream>>>(qbuf, DM, h,
        ln1g + (size_t)l*DM, ln1b + (size_t)l*DM, h, hhi, hlo);
    // ffn out (f32) = relu(h @ ffn_w^T + b) -> qbuf
    gemm_mfma<true><<<dim3(DM/128, MM/128), 256, 0, stream>>>(
        hhi, hlo, ffnw + (size_t)l*DM*DM, ffnb + (size_t)l*DM, qbuf, nullptr, nullptr, DM, DM, DM);
    // h = LN2(ffn + h), + split
    add_ln_kernel<<<MM, 256, 0, stream>>>(qbuf, DM, h,
        ln2g + (size_t)l*DM, ln2b + (size_t)l*DM, h, hhi, hlo);
  }
  (void)in_sizes; (void)n_in; (void)out_size; (void)ws_size;
}